// Round 10
// baseline (619.845 us; speedup 1.0000x reference)
//
#include <hip/hip_runtime.h>

// MSDNet on gfx950 — round 10: R8 structure + dilation-chained ROW PAIRS.
// Empirical law (R5/R7/R8): VMEM cost/CU ~= max(7cyc*instr, ~2cyc*L1-lines),
// no dedup between overlapping loads. R8 pays 3 rows x 3 octets per output
// row per plane. This round: one wave computes the PAIR {y, y+D} (dilation
// chain), which shares 2 of 4 input rows -> 4 rows/plane for 2 outputs
// (1.5x fewer loads & lines), and each shared row's windows feed both
// accumulators. Rows pair inside mod-D chains; slot->(chain,pair) is a
// <=10-iter wave-uniform scalar loop. 520 blocks x 128 thr = 1040 waves.
// Everything else identical to R8 (fp16 NCHW planes, HALO=16, aligned
// dwordx4 octets + alignbit windows, fp32 v_fma_mix, 2-deep plane pipeline).

#define MSD_DEPTH 30
#define NB 4
#define IH 512
#define IW 512
#define HALO 16
#define WPp (IW + 2 * HALO) /* 544 */
#define HPp (IH + 2 * HALO) /* 544 */
#define PLANE_E ((size_t)WPp * HPp)
#define CSTR ((size_t)NB * PLANE_E)
#define NPIX (NB * IH * IW)
#define NSLOT 260 /* max row-pair slots per batch over all D (D=9/10: 260) */

typedef _Float16 h2 __attribute__((ext_vector_type(2)));
typedef float f4 __attribute__((ext_vector_type(4)));
typedef unsigned int u32;

// ---------------------------------------------------------------------------
#define STRIPS_PER_SUB (2176 + 512 * 4) /* 4224 16B halo strips per subplane */
__global__ __launch_bounds__(256) void zero_halo_kernel(_Float16* __restrict__ feats) {
    int idx = blockIdx.x * 256 + threadIdx.x;
    const int total = STRIPS_PER_SUB * MSD_DEPTH * NB;
    if (idx >= total) return;
    int sub = idx / STRIPS_PER_SUB;
    int s = idx - sub * STRIPS_PER_SUB;
    int r, cpx;
    if (s < 2176) {
        int rr = s / 68;
        cpx = (s - rr * 68) * 8;
        r = (rr < 16) ? rr : (IH + HALO) + (rr - 16);
    } else {
        int t = s - 2176;
        r = HALO + t / 4;
        int j = t & 3;
        cpx = (j < 2) ? j * 8 : (IW + HALO) + (j - 2) * 8;
    }
    uint4 z = {0, 0, 0, 0};
    *(uint4*)(feats + (size_t)sub * PLANE_E + (size_t)r * WPp + cpx) = z;
}

// ---------------------------------------------------------------------------
__global__ __launch_bounds__(256) void scale_in_kernel(const float* __restrict__ x,
                                                       _Float16* __restrict__ feats,
                                                       const float* __restrict__ sw,
                                                       const float* __restrict__ sb) {
    int s = blockIdx.x * 256 + threadIdx.x;
    int idx = s * 8;
    int b = idx >> 18;
    int y = (idx >> 9) & 511;
    int xx = idx & 511;
    const float sws = sw[0], sbs = sb[0];
    _Float16 v[8];
#pragma unroll
    for (int j = 0; j < 8; ++j) v[j] = (_Float16)(x[idx + j] * sws + sbs);
    *(uint4*)(feats + (size_t)b * PLANE_E + (size_t)(y + HALO) * WPp + (xx + HALO)) =
        *(uint4*)v;
}

// ---------------------------------------------------------------------------
template <int SB>
__device__ __forceinline__ void win(const u32* cd, u32 w[4]) {
    constexpr int q = SB >> 2;
    if constexpr ((SB & 2) != 0) {
#pragma unroll
        for (int i = 0; i < 4; ++i)
            w[i] = __builtin_amdgcn_alignbit(cd[q + i + 1], cd[q + i], 16);
    } else {
#pragma unroll
        for (int i = 0; i < 4; ++i) w[i] = cd[q + i];
    }
}

__device__ __forceinline__ void fma8(float* acc, const u32* w, float wt) {
#pragma unroll
    for (int i = 0; i < 4; ++i) {
        h2 h = __builtin_bit_cast(h2, w[i]);
        acc[2 * i]     = fmaf((float)h[0], wt, acc[2 * i]);
        acc[2 * i + 1] = fmaf((float)h[1], wt, acc[2 * i + 1]);
    }
}

// ---------------------------------------------------------------------------
template <int I>
__global__ __launch_bounds__(128, 2) void depth_kernel(_Float16* __restrict__ feats,
                                                       const float* __restrict__ Wmsd,
                                                       const float* __restrict__ bias,
                                                       const float* __restrict__ convW,
                                                       const float* __restrict__ convB,
                                                       const float* __restrict__ soutw,
                                                       const float* __restrict__ soutb,
                                                       float* __restrict__ out) {
    constexpr int D = (I % 10) + 1;
    constexpr int NC = I + 1;
    constexpr bool LAST = (I == MSD_DEPTH - 1);
    constexpr bool WIDE = (D > 8);
    constexpr int NR = WIDE ? 5 : 3;   // octets per row
    constexpr int LQ = 512 / D, REM = 512 % D;

    const int tid = threadIdx.x;
    const int widx = tid >> 6, lane = tid & 63;
    const int u = blockIdx.x * 2 + widx; // wave-slot 0..1039
    const int b = u / NSLOT;
    int s = u - b * NSLOT;

    // slot -> (chain r, pair k): chain r = {y : y % D == r}, pairs of
    // consecutive chain elements. Wave-uniform scalar loop, <= D iters.
    int r = -1, len = 0;
    for (int rr = 0; rr < D; ++rr) {
        int ln = LQ + (rr < REM ? 1 : 0);
        int pr = (ln + 1) >> 1;
        if (s < pr) { r = rr; len = ln; break; }
        s -= pr;
    }
    if (r < 0) return; // surplus slot
    const int y0 = r + (2 * s) * D;
    const bool have2 = (2 * s + 1) < len;
    const int y1 = y0 + D;

    const _Float16* const base =
        feats + (size_t)b * PLANE_E + HALO + lane * 8;
    // input rows: y0-D, y0, y1(=y0+D), y1+D  (rows 0..3)
    const size_t roff[4] = {
        (size_t)(y0 - D + HALO) * WPp, (size_t)(y0 + HALO) * WPp,
        (size_t)(y1 + HALO) * WPp,     (size_t)(y1 + D + HALO) * WPp};

    float acc0[8], acc1[8], yd0[8], yd1[8];
#pragma unroll
    for (int j = 0; j < 8; ++j) { acc0[j] = acc1[j] = yd0[j] = yd1[j] = 0.f; }

    const float* const wrb = Wmsd + (size_t)I * (MSD_DEPTH * 9);

    uint4 A[4 * NR], B[4 * NR];

    auto load_rows = [&](uint4* o, int c) {
        const _Float16* pc = base + (size_t)c * CSTR;
#pragma unroll
        for (int rI = 0; rI < 4; ++rI) {
            if (rI == 3 && !have2) break;
            const _Float16* rp = pc + roff[rI];
            o[rI * NR + 0] = *(const uint4*)(rp - 8);
            o[rI * NR + 1] = *(const uint4*)(rp);
            o[rI * NR + 2] = *(const uint4*)(rp + 8);
            if constexpr (WIDE) {
                o[rI * NR + 3] = *(const uint4*)(rp - 16);
                o[rI * NR + 4] = *(const uint4*)(rp + 16);
            }
        }
    };

    // Build the 3 windows of one input row, hand them to f(wl, wc, wr).
    auto dorow = [&](const uint4* o, auto&& f) {
        u32 cd[20];
        *(uint4*)&cd[4] = o[0];
        *(uint4*)&cd[8] = o[1];
        *(uint4*)&cd[12] = o[2];
        if constexpr (WIDE) {
            *(uint4*)&cd[0] = o[3];
            *(uint4*)&cd[16] = o[4];
        }
        u32 wl[4], wr_[4];
        win<32 - 2 * D>(cd, wl);
        win<32 + 2 * D>(cd, wr_);
        f(wl, &cd[8], wr_);
    };

    auto compute = [&](const uint4* o, int c) {
        const float* wk = wrb + c * 9;
        const float w0 = wk[0], w1 = wk[1], w2 = wk[2], w3 = wk[3], w4 = wk[4],
                    w5 = wk[5], w6 = wk[6], w7 = wk[7], w8 = wk[8];
        const float cw = LAST ? convW[c] : 0.f;
        // row y0-D: top taps of out-y0
        dorow(o + 0 * NR, [&](u32* wl, u32* wc, u32* wr) {
            fma8(acc0, wl, w0); fma8(acc0, wc, w1); fma8(acc0, wr, w2);
        });
        // row y0: mid taps of out-y0, top taps of out-y1 (+1x1 for out-y0)
        dorow(o + 1 * NR, [&](u32* wl, u32* wc, u32* wr) {
            fma8(acc0, wl, w3); fma8(acc0, wc, w4); fma8(acc0, wr, w5);
            if (have2) { fma8(acc1, wl, w0); fma8(acc1, wc, w1); fma8(acc1, wr, w2); }
            if (LAST) fma8(yd0, wc, cw);
        });
        // row y1: bottom taps of out-y0, mid taps of out-y1 (+1x1 for out-y1)
        dorow(o + 2 * NR, [&](u32* wl, u32* wc, u32* wr) {
            fma8(acc0, wl, w6); fma8(acc0, wc, w7); fma8(acc0, wr, w8);
            if (have2) {
                fma8(acc1, wl, w3); fma8(acc1, wc, w4); fma8(acc1, wr, w5);
                if (LAST) fma8(yd1, wc, cw);
            }
        });
        // row y1+D: bottom taps of out-y1
        if (have2)
            dorow(o + 3 * NR, [&](u32* wl, u32* wc, u32* wr) {
                fma8(acc1, wl, w6); fma8(acc1, wc, w7); fma8(acc1, wr, w8);
            });
    };

    // 2-deep software pipeline over planes (validated R8).
    load_rows(A, 0);
    int c = 0;
    for (; c + 2 <= NC; c += 2) {
        load_rows(B, c + 1);
        compute(A, c);
        if (c + 2 < NC) load_rows(A, c + 2);
        compute(B, c + 1);
    }
    if (c < NC) compute(A, c);

    const float b0 = bias[I];
    if (!LAST) {
        _Float16* hp = feats + (size_t)NC * CSTR + (size_t)b * PLANE_E + HALO + lane * 8;
        _Float16 hv[8];
#pragma unroll
        for (int j = 0; j < 8; ++j) {
            float h = acc0[j] + b0;
            hv[j] = (_Float16)(h > 0.f ? h : 0.f);
        }
        *(uint4*)(hp + roff[1]) = *(uint4*)hv;
        if (have2) {
#pragma unroll
            for (int j = 0; j < 8; ++j) {
                float h = acc1[j] + b0;
                hv[j] = (_Float16)(h > 0.f ? h : 0.f);
            }
            *(uint4*)(hp + roff[2]) = *(uint4*)hv;
        }
    } else {
        const float cw29 = convW[MSD_DEPTH];
        const float cb = convB[0], ow = soutw[0], ob = soutb[0];
        {
            float* q = out + ((size_t)b * IH + y0) * IW + lane * 8;
            f4 o0, o1;
#pragma unroll
            for (int j = 0; j < 8; ++j) {
                float h = acc0[j] + b0;
                h = h > 0.f ? h : 0.f;
                float yv = yd0[j] + cw29 * h + cb;
                yv = yv * ow + ob;
                if (j < 4) o0[j] = yv; else o1[j - 4] = yv;
            }
            *(f4*)q = o0;
            *(f4*)(q + 4) = o1;
        }
        if (have2) {
            float* q = out + ((size_t)b * IH + y1) * IW + lane * 8;
            f4 o0, o1;
#pragma unroll
            for (int j = 0; j < 8; ++j) {
                float h = acc1[j] + b0;
                h = h > 0.f ? h : 0.f;
                float yv = yd1[j] + cw29 * h + cb;
                yv = yv * ow + ob;
                if (j < 4) o0[j] = yv; else o1[j - 4] = yv;
            }
            *(f4*)q = o0;
            *(f4*)(q + 4) = o1;
        }
    }
}

// ---------------------------------------------------------------------------
extern "C" void kernel_launch(void* const* d_in, const int* in_sizes, int n_in,
                              void* d_out, int out_size, void* d_ws, size_t ws_size,
                              hipStream_t stream) {
    const float* x     = (const float*)d_in[0];
    const float* Wmsd  = (const float*)d_in[1];
    const float* bias  = (const float*)d_in[2];
    const float* convW = (const float*)d_in[3];
    const float* convB = (const float*)d_in[4];
    const float* sinw  = (const float*)d_in[5];
    const float* sinb  = (const float*)d_in[6];
    const float* soutw = (const float*)d_in[7];
    const float* soutb = (const float*)d_in[8];
    float* out = (float*)d_out;
    _Float16* feats = (_Float16*)d_ws;

    const int strips = STRIPS_PER_SUB * MSD_DEPTH * NB;
    zero_halo_kernel<<<(strips + 255) / 256, 256, 0, stream>>>(feats);
    scale_in_kernel<<<NPIX / 8 / 256, 256, 0, stream>>>(x, feats, sinw, sinb);

#define LNCH(I) depth_kernel<I><<<(NB * NSLOT) / 2, 128, 0, stream>>>(feats, Wmsd, bias, convW, convB, soutw, soutb, out);
    LNCH(0)  LNCH(1)  LNCH(2)  LNCH(3)  LNCH(4)
    LNCH(5)  LNCH(6)  LNCH(7)  LNCH(8)  LNCH(9)
    LNCH(10) LNCH(11) LNCH(12) LNCH(13) LNCH(14)
    LNCH(15) LNCH(16) LNCH(17) LNCH(18) LNCH(19)
    LNCH(20) LNCH(21) LNCH(22) LNCH(23) LNCH(24)
    LNCH(25) LNCH(26) LNCH(27) LNCH(28) LNCH(29)
#undef LNCH
}

// Round 12
// 395.311 us; speedup vs baseline: 1.5680x; 1.5680x over previous
//
#include <hip/hip_runtime.h>

// MSDNet on gfx950 — round 12: round-11 (paired-channel fdot2 + bpermute
// windows) with the D>8 window bug fixed. R11 failed because the horizontal
// window code indexed d[8-D+j] (negative for D=9,10) and only edge-masked
// lanes 0/63, while D>8 windows reach 2 lanes away. Fix: generalized window
// extractor — for tap offset off=k±D: src lane = lane+(off>>3) (floor, -2..2),
// reg idx = off-8*(off>>3), ds_bpermute from the ±1/±2 lane, validity mask
// lane>=-q / lane<=63-q == conv zero-padding. All constant-folded per k.
// Layout: feats = 15 channel-pairs (u32 = 2xf16) x 4 batches x 544x544;
// one wave = one 512-px row (8 px/lane); 1024x128 grid (8 waves/CU), XCD
// bands; fdot2 contracts 2 ch/px/tap; 2-deep pair pipeline; weights packed
// to f16 pairs. Depth 29 fuses 1x1 conv + output affine.

#define MSD_DEPTH 30
#define NB 4
#define IH 512
#define IW 512
#define HALO 16
#define WPp (IW + 2 * HALO)               /* 544 u32 per row */
#define HPp (IH + 2 * HALO)               /* 544 rows */
#define PLANE_U ((size_t)WPp * HPp)       /* u32 per subplane */
#define PSTR ((size_t)NB * PLANE_U)       /* pair stride (u32) */
#define NPAIR 15
#define NPIX (NB * IH * IW)
#define WPK_OFF ((size_t)20 << 20)        /* u32 offset: 80 MB into ws */

typedef _Float16 h2v __attribute__((ext_vector_type(2)));
typedef unsigned int u32;

__device__ __forceinline__ float fdot2u(u32 a, u32 b, float c) {
#if __has_builtin(__builtin_amdgcn_fdot2)
    return __builtin_amdgcn_fdot2(__builtin_bit_cast(h2v, a),
                                  __builtin_bit_cast(h2v, b), c, false);
#else
    h2v x = __builtin_bit_cast(h2v, a), y = __builtin_bit_cast(h2v, b);
    return c + (float)x[0] * (float)y[0] + (float)x[1] * (float)y[1];
#endif
}

// ---------------------------------------------------------------------------
__global__ __launch_bounds__(256) void pack_weights(const float* __restrict__ Wmsd,
                                                    const float* __restrict__ convW,
                                                    u32* __restrict__ wpk,
                                                    u32* __restrict__ cpk) {
    int idx = blockIdx.x * 256 + threadIdx.x;
    if (idx < MSD_DEPTH * NPAIR * 9) {
        int I = idx / (NPAIR * 9);
        int rem = idx - I * (NPAIR * 9);
        int p = rem / 9, t = rem - p * 9;
        int NC = I + 1, c0 = 2 * p, c1 = 2 * p + 1;
        h2v pk;
        pk[0] = (_Float16)((c0 < NC) ? Wmsd[((size_t)I * MSD_DEPTH + c0) * 9 + t] : 0.f);
        pk[1] = (_Float16)((c1 < NC) ? Wmsd[((size_t)I * MSD_DEPTH + c1) * 9 + t] : 0.f);
        wpk[idx] = __builtin_bit_cast(u32, pk);
    }
    if (idx < NPAIR) {
        h2v pk;
        pk[0] = (_Float16)convW[2 * idx];
        pk[1] = (_Float16)convW[2 * idx + 1];
        cpk[idx] = __builtin_bit_cast(u32, pk);
    }
}

// ---------------------------------------------------------------------------
// Zero top/bottom 16 full rows of all 60 subplanes (side halos never read:
// horizontal zero-pad is synthesized by the bpermute validity masks).
__global__ __launch_bounds__(256) void zero_halo_kernel(u32* __restrict__ feats) {
    const int per = 32 * (WPp / 4); // 32 rows x 136 uint4 strips = 4352
    int idx = blockIdx.x * 256 + threadIdx.x;
    if (idx >= per * NPAIR * NB) return;
    int sub = idx / per;
    int s = idx - sub * per;
    int rr = s / 136;
    int c4 = (s - rr * 136) * 4;
    int r = (rr < 16) ? rr : (IH + HALO) + (rr - 16);
    uint4 z = {0, 0, 0, 0};
    *(uint4*)(feats + (size_t)sub * PLANE_U + (size_t)r * WPp + c4) = z;
}

// ---------------------------------------------------------------------------
// Pair 0 lo16 = f16(x*sin_w+sin_b), hi16 = 0 (h0 merged in by depth 0).
__global__ __launch_bounds__(256) void scale_in_kernel(const float* __restrict__ x,
                                                       u32* __restrict__ feats,
                                                       const float* __restrict__ sw,
                                                       const float* __restrict__ sb) {
    int s = blockIdx.x * 256 + threadIdx.x;
    int idx = s * 8;
    int b = idx >> 18;
    int y = (idx >> 9) & 511;
    int xx = idx & 511;
    const float sws = sw[0], sbs = sb[0];
    u32 v[8];
#pragma unroll
    for (int j = 0; j < 8; ++j) {
        _Float16 h = (_Float16)(x[idx + j] * sws + sbs);
        v[j] = (u32)__builtin_bit_cast(unsigned short, h);
    }
    u32* q = feats + (size_t)b * PLANE_U + (size_t)(y + HALO) * WPp + HALO + xx;
    *(uint4*)q = *(uint4*)&v[0];
    *(uint4*)(q + 4) = *(uint4*)&v[4];
}

// ---------------------------------------------------------------------------
template <int I>
__global__ __launch_bounds__(128, 2) void depth_kernel(u32* __restrict__ feats,
                                                       const u32* __restrict__ wpk,
                                                       const u32* __restrict__ cpk,
                                                       const float* __restrict__ bias,
                                                       const float* __restrict__ convW,
                                                       const float* __restrict__ convB,
                                                       const float* __restrict__ soutw,
                                                       const float* __restrict__ soutb,
                                                       float* __restrict__ out) {
    constexpr int D = (I % 10) + 1;
    constexpr int NC = I + 1;
    constexpr int NP = (NC + 1) / 2;
    constexpr bool LAST = (I == MSD_DEPTH - 1);

    const int tid = threadIdx.x;
    const int widx = tid >> 6, lane = tid & 63;
    const int bid = blockIdx.x; // 1024 blocks x 2 waves = 2048 waves = rows
    // XCD band swizzle (validated R4-R8): 2 XCDs per image, contiguous bands.
    const int xcd = bid & 7;
    const int kk = bid >> 3; // 0..127
    const int b = xcd >> 1;
    const int y = (xcd & 1) * 256 + kk * 2 + widx;

    // bpermute byte addresses for lane offsets -2,-1,+1,+2 (wrap is masked).
    const int bp_m2 = ((lane - 2) & 63) << 2;
    const int bp_m1 = ((lane - 1) & 63) << 2;
    const int bp_p1 = ((lane + 1) & 63) << 2;
    const int bp_p2 = ((lane + 2) & 63) << 2;

    u32* const pb = feats + (size_t)b * PLANE_U + (size_t)(y + HALO) * WPp + HALO + lane * 8;

    float acc[8], ydot[8];
#pragma unroll
    for (int j = 0; j < 8; ++j) { acc[j] = 0.f; ydot[j] = 0.f; }

    const u32* const wrb = wpk + (size_t)I * (NPAIR * 9);

    u32 A[3][8], B[3][8];

    auto load_pair = [&](u32 (*buf)[8], int p) {
        const u32* pp = pb + (size_t)p * PSTR;
#pragma unroll
        for (int r = 0; r < 3; ++r) {
            const u32* rp = pp + (ptrdiff_t)(r - 1) * (D * WPp);
            *(uint4*)&buf[r][0] = *(const uint4*)rp;
            *(uint4*)&buf[r][4] = *(const uint4*)(rp + 4);
        }
    };

    // w[k] = dword at row-pixel (lane*8 + k + shift), 0 outside [0,512).
    auto window = [&](const u32* d, int shift, u32* w) {
#pragma unroll
        for (int k = 0; k < 8; ++k) {
            int off = k + shift; // constant-folded (shift = +-D, k unrolled)
            if (off >= 0 && off < 8) {
                w[k] = d[off];
            } else {
                int q = off >> 3;            // floor div 8: -2,-1,1,2
                int idx = off - q * 8;       // 0..7
                int addr = (q == -2) ? bp_m2
                         : (q == -1) ? bp_m1
                         : (q == 1)  ? bp_p1 : bp_p2;
                u32 t = (u32)__builtin_amdgcn_ds_bpermute(addr, (int)d[idx]);
                bool valid = (q < 0) ? (lane >= -q) : (lane <= 63 - q);
                w[k] = valid ? t : 0u;
            }
        }
    };

    auto compute = [&](u32 (*buf)[8], int p) {
        const u32* wq = wrb + p * 9; // wave-uniform -> s_load
        const u32 cw = LAST ? cpk[p] : 0u;
#pragma unroll
        for (int r = 0; r < 3; ++r) {
            u32* d = buf[r];
            u32 wl[8], wrr[8];
            window(d, -D, wl);
            window(d, D, wrr);
            const u32 w0 = wq[r * 3 + 0], w1 = wq[r * 3 + 1], w2 = wq[r * 3 + 2];
#pragma unroll
            for (int k = 0; k < 8; ++k) {
                float a = acc[k];
                a = fdot2u(wl[k], w0, a);
                a = fdot2u(d[k], w1, a);
                a = fdot2u(wrr[k], w2, a);
                acc[k] = a;
            }
            if (LAST && r == 1) {
#pragma unroll
                for (int k = 0; k < 8; ++k) ydot[k] = fdot2u(d[k], cw, ydot[k]);
            }
        }
    };

    // 2-deep software pipeline over channel pairs (validated R8).
    load_pair(A, 0);
    int p = 0;
    for (; p + 2 <= NP; p += 2) {
        load_pair(B, p + 1);
        compute(A, p);
        if (p + 2 < NP) load_pair(A, p + 2);
        compute(B, p + 1);
    }
    if (p < NP) compute(A, p);

    const float b0 = bias[I];
    if (!LAST) {
        // Merge h (channel NC) into pair NC>>1. NC odd: hi16 (partner lo16 =
        // channel NC-1, reloaded L2-hot). NC even: lo16, hi16 = 0.
        u32 part[8];
        if constexpr ((NC & 1) != 0) {
            const u32* rp = pb + (size_t)(NP - 1) * PSTR;
            *(uint4*)&part[0] = *(const uint4*)rp;
            *(uint4*)&part[4] = *(const uint4*)(rp + 4);
        }
        u32 mg[8];
#pragma unroll
        for (int j = 0; j < 8; ++j) {
            float h = acc[j] + b0;
            h = h > 0.f ? h : 0.f;
            u32 h16 = (u32)__builtin_bit_cast(unsigned short, (_Float16)h);
            if constexpr ((NC & 1) != 0)
                mg[j] = (part[j] & 0xFFFFu) | (h16 << 16);
            else
                mg[j] = h16;
        }
        u32* q = feats + (size_t)(NC >> 1) * PSTR + (size_t)b * PLANE_U +
                 (size_t)(y + HALO) * WPp + HALO + lane * 8;
        *(uint4*)q = *(uint4*)&mg[0];
        *(uint4*)(q + 4) = *(uint4*)&mg[4];
    } else {
        const float cw30 = convW[MSD_DEPTH];
        const float cb = convB[0], ow = soutw[0], ob = soutb[0];
        float* q = out + ((size_t)b * IH + y) * IW + lane * 8;
        float o[8];
#pragma unroll
        for (int j = 0; j < 8; ++j) {
            float h = acc[j] + b0;
            h = h > 0.f ? h : 0.f;
            float yv = ydot[j] + cw30 * h + cb;
            o[j] = yv * ow + ob;
        }
        *(uint4*)q = *(uint4*)&o[0];
        *(uint4*)(q + 4) = *(uint4*)&o[4];
    }
}

// ---------------------------------------------------------------------------
extern "C" void kernel_launch(void* const* d_in, const int* in_sizes, int n_in,
                              void* d_out, int out_size, void* d_ws, size_t ws_size,
                              hipStream_t stream) {
    const float* x     = (const float*)d_in[0];
    const float* Wmsd  = (const float*)d_in[1];
    const float* bias  = (const float*)d_in[2];
    const float* convW = (const float*)d_in[3];
    const float* convB = (const float*)d_in[4];
    const float* sinw  = (const float*)d_in[5];
    const float* sinb  = (const float*)d_in[6];
    const float* soutw = (const float*)d_in[7];
    const float* soutb = (const float*)d_in[8];
    float* out = (float*)d_out;

    u32* feats = (u32*)d_ws;                 // 15 pairs x 4 b x 544x544 u32 = 71 MB
    u32* wpk = feats + WPK_OFF;              // 80 MB offset
    u32* cpk = wpk + MSD_DEPTH * NPAIR * 9;

    pack_weights<<<16, 256, 0, stream>>>(Wmsd, convW, wpk, cpk);

    const int zstrips = 32 * (WPp / 4) * NPAIR * NB; // 261120
    zero_halo_kernel<<<(zstrips + 255) / 256, 256, 0, stream>>>(feats);

    scale_in_kernel<<<NPIX / 8 / 256, 256, 0, stream>>>(x, feats, sinw, sinb);

#define LNCH(I) depth_kernel<I><<<1024, 128, 0, stream>>>(feats, wpk, cpk, bias, convW, convB, soutw, soutb, out);
    LNCH(0)  LNCH(1)  LNCH(2)  LNCH(3)  LNCH(4)
    LNCH(5)  LNCH(6)  LNCH(7)  LNCH(8)  LNCH(9)
    LNCH(10) LNCH(11) LNCH(12) LNCH(13) LNCH(14)
    LNCH(15) LNCH(16) LNCH(17) LNCH(18) LNCH(19)
    LNCH(20) LNCH(21) LNCH(22) LNCH(23) LNCH(24)
    LNCH(25) LNCH(26) LNCH(27) LNCH(28) LNCH(29)
#undef LNCH
}